// Round 7
// baseline (78.164 us; speedup 1.0000x reference)
//
#include <hip/hip_runtime.h>

#define B_TOTAL 32768
#define NROWB   64             // rows per block
#define TILE    16             // rows per tile
#define NT      4              // tiles per block

typedef __attribute__((ext_vector_type(8)))  short    bf16x8;
typedef __attribute__((ext_vector_type(4)))  float    f32x4;
typedef __attribute__((ext_vector_type(4)))  unsigned u32x4;

// round-to-nearest-even fp32 -> bf16 (weights, one-time)
__device__ __forceinline__ unsigned rne1(float f) {
    unsigned u = __builtin_bit_cast(unsigned, f);
    return (u + 0x7FFFu + ((u >> 16) & 1u)) >> 16;
}
// HW packed fp32x2 -> bf16x2 (gfx950; no builtin)
__device__ __forceinline__ unsigned cvtpk(float lo, float hi) {
    unsigned r;
    asm("v_cvt_pk_bf16_f32 %0, %1, %2" : "=v"(r) : "v"(lo), "v"(hi));
    return r;
}
__device__ __forceinline__ float fsig(float v) {
    return __fdividef(1.0f, 1.0f + __expf(-v));
}
__device__ __forceinline__ float ftanh(float v) {
    return 1.0f - __fdividef(2.0f, 1.0f + __expf(2.0f * v));
}

// Weights -> fragment-linear bf16 for mfma 16x16x32.
// Frag F = cs*32 + g*8 + ks; lane l: W_g[n = cs*16 + (l&15)][k = ks*32 + (l>>4)*8 + e]
__global__ void wconv_kernel(const float* __restrict__ w1, const float* __restrict__ w2,
                             const float* __restrict__ wf, const float* __restrict__ w3,
                             u32x4* __restrict__ out) {
    int T = blockIdx.x * 256 + threadIdx.x;   // 16384 threads
    int F = T >> 6, l = T & 63;
    int cs = F >> 5, g = (F >> 3) & 3, ks = F & 7;
    const float* W = (g == 0) ? w1 : (g == 1) ? w2 : (g == 2) ? wf : w3;
    const float* s = W + (cs * 16 + (l & 15)) * 256 + ks * 32 + (l >> 4) * 8;
    f32x4 lo = *(const f32x4*)s;
    f32x4 hi = *(const f32x4*)(s + 4);
    u32x4 r;
    r[0] = rne1(lo[0]) | (rne1(lo[1]) << 16);
    r[1] = rne1(lo[2]) | (rne1(lo[3]) << 16);
    r[2] = rne1(hi[0]) | (rne1(hi[1]) << 16);
    r[3] = rne1(hi[2]) | (rne1(hi[3]) << 16);
    out[T] = r;
}

// Block: 8 waves (512 thr) = all 128 output cols; 64 rows as 4 tiles of 16.
// Wave w: col-slice cs=w, ALL 4 gates; weights resident in 128 VGPRs.
// Grid 512 -> 2 blocks/CU, 16 waves/CU, 4 waves/SIMD (LDS 32 KB/block).
__global__ __launch_bounds__(512, 4) void lstm_kernel(
    const float* __restrict__ x, const float* __restrict__ h, const float* __restrict__ c,
    const bf16x8* __restrict__ wfrag,
    const float* __restrict__ b1, const float* __restrict__ b2,
    const float* __restrict__ bfv, const float* __restrict__ b3,
    float* __restrict__ out)
{
    __shared__ __align__(16) char smem[2][TILE * 1024];   // 32 KB

    const int tid  = threadIdx.x;
    const int wave = tid >> 6;                // col-slice 0..7
    const int lane = tid & 63;
    const long row0 = (long)blockIdx.x * NROWB;
    const int rb    = lane & 15;              // batch row within tile
    const int gcol4 = wave * 16 + (lane >> 4) * 4;  // 4 consecutive gate cols

    // ---- stage tile t (16 rows x 256 fp32) into smem[t&1], async ----
    auto STAGE = [&](int t) {
        char* buf = smem[t & 1];
        const long gr0 = row0 + (long)t * TILE;
#pragma unroll
        for (int i = 0; i < 2; ++i) {
            const int r = wave * 2 + i;
            const unsigned kb = ((unsigned)lane * 16u) ^ (((unsigned)r & 7u) << 4);
            const float* src = (kb < 512u)
                ? (x + (gr0 + r) * 128 + (kb >> 2))
                : (h + (gr0 + r) * 128 + ((kb - 512u) >> 2));
            __builtin_amdgcn_global_load_lds(
                (const __attribute__((address_space(1))) unsigned*)src,
                (__attribute__((address_space(3))) unsigned*)(buf + r * 1024),
                16, 0, 0);
        }
    };

    STAGE(0);

    // ---- weights: 4 gates x 8 ks fragments -> 128 VGPRs, loaded once ----
    bf16x8 wfr[4][8];
#pragma unroll
    for (int g = 0; g < 4; ++g)
#pragma unroll
        for (int ks = 0; ks < 8; ++ks)
            wfr[g][ks] = wfrag[(size_t)(wave * 32 + g * 8 + ks) * 64 + lane];

    f32x4 bias[4];
    bias[0] = *(const f32x4*)(b1 + gcol4);
    bias[1] = *(const f32x4*)(b2 + gcol4);
    bias[2] = *(const f32x4*)(bfv + gcol4);
    bias[3] = *(const f32x4*)(b3 + gcol4);

    float* out_h = out;
    float* out_c = out + (size_t)B_TOTAL * 128;

#pragma unroll 1
    for (int t = 0; t < NT; ++t) {
        __syncthreads();                  // stage(t) complete; buf(t+1) free

        const long gr0 = row0 + (long)t * TILE;
        // c prefetch FIRST (so epilogue's vmcnt wait doesn't drain the stage)
        f32x4 cv = *(const f32x4*)(c + (gr0 + rb) * 128 + gcol4);

        if (t + 1 < NT) STAGE(t + 1);     // fills other buffer under compute(t)

        const char* buf = smem[t & 1];

        f32x4 acc[4];                     // one per gate
#pragma unroll
        for (int g = 0; g < 4; ++g) acc[g] = (f32x4){0.f, 0.f, 0.f, 0.f};

#pragma unroll
        for (int ks = 0; ks < 8; ++ks) {
            const unsigned swz = ((unsigned)rb & 7u) << 4;
            const unsigned kb  = (unsigned)(ks * 128 + (lane >> 4) * 32);
            const char* p = buf + rb * 1024;
            f32x4 a0 = *(const f32x4*)(p + (kb ^ swz));
            f32x4 a1 = *(const f32x4*)(p + ((kb + 16u) ^ swz));
            union { unsigned u[4]; bf16x8 v; } pk;
            pk.u[0] = cvtpk(a0[0], a0[1]);
            pk.u[1] = cvtpk(a0[2], a0[3]);
            pk.u[2] = cvtpk(a1[0], a1[1]);
            pk.u[3] = cvtpk(a1[2], a1[3]);
#pragma unroll
            for (int g = 0; g < 4; ++g)   // swapped operands: D[gatecol][batchrow]
                acc[g] = __builtin_amdgcn_mfma_f32_16x16x32_bf16(wfr[g][ks], pk.v, acc[g], 0, 0, 0);
        }

        // epilogue: in-register combine, float4 stores
        f32x4 nh, nc;
#pragma unroll
        for (int j = 0; j < 4; ++j) {
            const float g1 = fsig(acc[0][j] + bias[0][j]);
            const float g2 = fsig(acc[1][j] + bias[1][j]);
            const float gf = ftanh(acc[2][j] + bias[2][j]);
            const float g3 = fsig(acc[3][j] + bias[3][j]);
            nc[j] = cv[j] * g1 + g2 * gf;
            nh[j] = ftanh(nc[j]) * g3;
        }
        const long o = (gr0 + rb) * 128 + gcol4;
        *(f32x4*)(out_h + o) = nh;
        *(f32x4*)(out_c + o) = nc;
    }
}

extern "C" void kernel_launch(void* const* d_in, const int* in_sizes, int n_in,
                              void* d_out, int out_size, void* d_ws, size_t ws_size,
                              hipStream_t stream) {
    (void)in_sizes; (void)n_in; (void)out_size; (void)ws_size;
    const float* x  = (const float*)d_in[0];
    const float* h  = (const float*)d_in[1];
    const float* c  = (const float*)d_in[2];
    const float* W1 = (const float*)d_in[3];
    const float* b1 = (const float*)d_in[4];
    const float* W2 = (const float*)d_in[5];
    const float* b2 = (const float*)d_in[6];
    const float* Wf = (const float*)d_in[7];
    const float* bf = (const float*)d_in[8];
    const float* W3 = (const float*)d_in[9];
    const float* b3 = (const float*)d_in[10];

    wconv_kernel<<<64, 256, 0, stream>>>(W1, W2, Wf, W3, (u32x4*)d_ws);
    lstm_kernel<<<B_TOTAL / NROWB, 512, 0, stream>>>(
        x, h, c, (const bf16x8*)d_ws, b1, b2, bf, b3, (float*)d_out);
}

// Round 8
// 42.732 us; speedup vs baseline: 1.8292x; 1.8292x over previous
//
#include <hip/hip_runtime.h>

#define B_TOTAL 32768
#define NROWB   128            // rows per block
#define TILE    16             // rows per tile
#define NT      8              // tiles per block

typedef __attribute__((ext_vector_type(8)))  short    bf16x8;
typedef __attribute__((ext_vector_type(4)))  float    f32x4;
typedef __attribute__((ext_vector_type(4)))  unsigned u32x4;

// round-to-nearest-even fp32 -> bf16 (weights, one-time)
__device__ __forceinline__ unsigned rne1(float f) {
    unsigned u = __builtin_bit_cast(unsigned, f);
    return (u + 0x7FFFu + ((u >> 16) & 1u)) >> 16;
}
// HW packed fp32x2 -> bf16x2 (gfx950; no builtin)
__device__ __forceinline__ unsigned cvtpk(float lo, float hi) {
    unsigned r;
    asm("v_cvt_pk_bf16_f32 %0, %1, %2" : "=v"(r) : "v"(lo), "v"(hi));
    return r;
}
__device__ __forceinline__ float fsig(float v) {
    return __fdividef(1.0f, 1.0f + __expf(-v));
}
__device__ __forceinline__ float ftanh(float v) {
    return 1.0f - __fdividef(2.0f, 1.0f + __expf(2.0f * v));
}

// Weights -> fragment-linear bf16 for mfma 16x16x32.
// Frag F = cs*32 + g*8 + ks; lane l: W_g[n = cs*16 + (l&15)][k = ks*32 + (l>>4)*8 + e]
__global__ void wconv_kernel(const float* __restrict__ w1, const float* __restrict__ w2,
                             const float* __restrict__ wf, const float* __restrict__ w3,
                             u32x4* __restrict__ out) {
    int T = blockIdx.x * 256 + threadIdx.x;   // 16384 threads
    int F = T >> 6, l = T & 63;
    int cs = F >> 5, g = (F >> 3) & 3, ks = F & 7;
    const float* W = (g == 0) ? w1 : (g == 1) ? w2 : (g == 2) ? wf : w3;
    const float* s = W + (cs * 16 + (l & 15)) * 256 + ks * 32 + (l >> 4) * 8;
    f32x4 lo = *(const f32x4*)s;
    f32x4 hi = *(const f32x4*)(s + 4);
    u32x4 r;
    r[0] = rne1(lo[0]) | (rne1(lo[1]) << 16);
    r[1] = rne1(lo[2]) | (rne1(lo[3]) << 16);
    r[2] = rne1(hi[0]) | (rne1(hi[1]) << 16);
    r[3] = rne1(hi[2]) | (rne1(hi[3]) << 16);
    out[T] = r;
}

// Block: 8 waves = 4 wave-PAIRS. Pair pr owns 16 cols (cs = cg*4+pr).
// Role 0 wave: resident W1,W2 frags (64 VGPR); role 1: Wf,W3.
// Both roles stream the same A-tiles; pair exchanges raw pre-activations
// via padded LDS; role 0 stores new_h, role 1 stores new_c.
// ~115 VGPR/thread -> honest __launch_bounds__(512,4): 4 waves/SIMD.
__global__ __launch_bounds__(512, 4) void lstm_kernel(
    const float* __restrict__ x, const float* __restrict__ h, const float* __restrict__ c,
    const bf16x8* __restrict__ wfrag,
    const float* __restrict__ b1, const float* __restrict__ b2,
    const float* __restrict__ bfv, const float* __restrict__ b3,
    float* __restrict__ out)
{
    __shared__ __align__(16) char smem[2][TILE * 1024];   // 32 KB A-tile dbuf (fp32)
    __shared__ float ex[4][2][2][TILE][17];               // 17408 B exchange, +1 pad

    const int tid  = threadIdx.x;
    const int wave = tid >> 6;                // 0..7
    const int lane = tid & 63;
    const int pr   = wave >> 1;               // pair 0..3
    const int ro   = wave & 1;                // 0: gates W1,W2 | 1: gates Wf,W3
    const int cg   = blockIdx.x & 1;
    const long row0 = (long)(blockIdx.x >> 1) * NROWB;
    const int cs   = cg * 4 + pr;
    const int rb   = lane & 15;               // batch row within tile
    const int c4   = lane >> 4;
    const int gcol4 = cs * 16 + c4 * 4;       // 4 consecutive gate cols

    // ---- stage tile t (16 rows x 256 fp32) async; source-side XOR swizzle ----
    auto STAGE = [&](int t) {
        char* buf = smem[t & 1];
        const long gr0 = row0 + (long)t * TILE;
#pragma unroll
        for (int i = 0; i < 2; ++i) {
            const int r = wave * 2 + i;
            const unsigned kb = ((unsigned)lane * 16u) ^ (((unsigned)r & 7u) << 4);
            const float* src = (kb < 512u)
                ? (x + (gr0 + r) * 128 + (kb >> 2))
                : (h + (gr0 + r) * 128 + ((kb - 512u) >> 2));
            __builtin_amdgcn_global_load_lds(
                (const __attribute__((address_space(1))) unsigned*)src,
                (__attribute__((address_space(3))) unsigned*)(buf + r * 1024),
                16, 0, 0);
        }
    };

    STAGE(0);

    // ---- resident weights: 2 gates x 8 ks -> 64 VGPRs ----
    bf16x8 wfr[2][8];
#pragma unroll
    for (int g = 0; g < 2; ++g)
#pragma unroll
        for (int ks = 0; ks < 8; ++ks)
            wfr[g][ks] = wfrag[(size_t)(cs * 32 + (ro * 2 + g) * 8 + ks) * 64 + lane];

    f32x4 bias[2];
    if (ro == 0) {
        bias[0] = *(const f32x4*)(b1 + gcol4);
        bias[1] = *(const f32x4*)(b2 + gcol4);
    } else {
        bias[0] = *(const f32x4*)(bfv + gcol4);
        bias[1] = *(const f32x4*)(b3 + gcol4);
    }

    float* out_h = out;
    float* out_c = out + (size_t)B_TOTAL * 128;
    float* mystore = (ro == 0) ? out_h : out_c;

#pragma unroll 1
    for (int t = 0; t < NT; ++t) {
        __syncthreads();                  // stage(t) visible; ex(t-1) reads done

        const long gr0 = row0 + (long)t * TILE;
        f32x4 cv = *(const f32x4*)(c + (gr0 + rb) * 128 + gcol4);

        if (t + 1 < NT) STAGE(t + 1);

        const char* buf = smem[t & 1];

        f32x4 acc[2];
        acc[0] = (f32x4){0.f, 0.f, 0.f, 0.f};
        acc[1] = (f32x4){0.f, 0.f, 0.f, 0.f};

#pragma unroll
        for (int ks = 0; ks < 8; ++ks) {
            const unsigned swz = ((unsigned)rb & 7u) << 4;
            const unsigned kb  = (unsigned)(ks * 128 + c4 * 32);
            const char* p = buf + rb * 1024;
            f32x4 a0 = *(const f32x4*)(p + (kb ^ swz));
            f32x4 a1 = *(const f32x4*)(p + ((kb + 16u) ^ swz));
            union { unsigned u[4]; bf16x8 v; } pk;
            pk.u[0] = cvtpk(a0[0], a0[1]);
            pk.u[1] = cvtpk(a0[2], a0[3]);
            pk.u[2] = cvtpk(a1[0], a1[1]);
            pk.u[3] = cvtpk(a1[2], a1[3]);
            acc[0] = __builtin_amdgcn_mfma_f32_16x16x32_bf16(wfr[0][ks], pk.v, acc[0], 0, 0, 0);
            acc[1] = __builtin_amdgcn_mfma_f32_16x16x32_bf16(wfr[1][ks], pk.v, acc[1], 0, 0, 0);
        }

        // bias-add in place, publish to partner
#pragma unroll
        for (int g = 0; g < 2; ++g)
#pragma unroll
            for (int j = 0; j < 4; ++j) {
                const float v = acc[g][j] + bias[g][j];
                acc[g][j] = v;
                ex[pr][ro][g][rb][c4 * 4 + j] = v;
            }
        __syncthreads();                  // exchange visible

        f32x4 po0, po1;
#pragma unroll
        for (int j = 0; j < 4; ++j) {
            po0[j] = ex[pr][1 - ro][0][rb][c4 * 4 + j];
            po1[j] = ex[pr][1 - ro][1][rb][c4 * 4 + j];
        }

        f32x4 st;
#pragma unroll
        for (int j = 0; j < 4; ++j) {
            const float a1v = (ro == 0) ? acc[0][j] : po0[j];
            const float a2v = (ro == 0) ? acc[1][j] : po1[j];
            const float afv = (ro == 0) ? po0[j]    : acc[0][j];
            const float a3v = (ro == 0) ? po1[j]    : acc[1][j];
            const float G1 = fsig(a1v);
            const float G2 = fsig(a2v);
            const float GF = ftanh(afv);
            const float ncv = cv[j] * G1 + G2 * GF;
            st[j] = (ro == 0) ? ftanh(ncv) * fsig(a3v) : ncv;   // role0: new_h, role1: new_c
        }
        *(f32x4*)(mystore + (gr0 + rb) * 128 + gcol4) = st;
    }
}

extern "C" void kernel_launch(void* const* d_in, const int* in_sizes, int n_in,
                              void* d_out, int out_size, void* d_ws, size_t ws_size,
                              hipStream_t stream) {
    (void)in_sizes; (void)n_in; (void)out_size; (void)ws_size;
    const float* x  = (const float*)d_in[0];
    const float* h  = (const float*)d_in[1];
    const float* c  = (const float*)d_in[2];
    const float* W1 = (const float*)d_in[3];
    const float* b1 = (const float*)d_in[4];
    const float* W2 = (const float*)d_in[5];
    const float* b2 = (const float*)d_in[6];
    const float* Wf = (const float*)d_in[7];
    const float* bf = (const float*)d_in[8];
    const float* W3 = (const float*)d_in[9];
    const float* b3 = (const float*)d_in[10];

    wconv_kernel<<<64, 256, 0, stream>>>(W1, W2, Wf, W3, (u32x4*)d_ws);
    lstm_kernel<<<B_TOTAL / NROWB * 2, 512, 0, stream>>>(
        x, h, c, (const bf16x8*)d_ws, b1, b2, bf, b3, (float*)d_out);
}

// Round 9
// 40.015 us; speedup vs baseline: 1.9534x; 1.0679x over previous
//
#include <hip/hip_runtime.h>

#define B_TOTAL 32768
#define NROWB   128            // rows per block
#define TILE    16             // rows per tile
#define NT      8              // tiles per block

typedef __attribute__((ext_vector_type(8)))  short    bf16x8;
typedef __attribute__((ext_vector_type(4)))  float    f32x4;
typedef __attribute__((ext_vector_type(4)))  unsigned u32x4;

// round-to-nearest-even fp32 -> bf16 (weights, one-time)
__device__ __forceinline__ unsigned rne1(float f) {
    unsigned u = __builtin_bit_cast(unsigned, f);
    return (u + 0x7FFFu + ((u >> 16) & 1u)) >> 16;
}
// HW packed fp32x2 -> bf16x2 (gfx950; no builtin)
__device__ __forceinline__ unsigned cvtpk(float lo, float hi) {
    unsigned r;
    asm("v_cvt_pk_bf16_f32 %0, %1, %2" : "=v"(r) : "v"(lo), "v"(hi));
    return r;
}
__device__ __forceinline__ float fsig(float v) {
    return __fdividef(1.0f, 1.0f + __expf(-v));
}
__device__ __forceinline__ float ftanh(float v) {
    return 1.0f - __fdividef(2.0f, 1.0f + __expf(2.0f * v));
}

// Weights -> COMPOSITE gate-interleaved fragments for mfma 16x16x32.
// Frag F = (s*2 + tau)*8 + ks, s = 8-hcol slice 0..15, tau = half 0..1.
// B-col n16 = hl*4 + g  (hl = local hcol 0..3, g = gate) -- so D's j-index
// (n16 = c4*4 + j) gives lane all 4 GATES of one hcol.
// Lane l: n16 = l&15 -> g = n16&3, hl = n16>>2;
//   element = W_g[hcol = s*8 + tau*4 + hl][k = ks*32 + (l>>4)*8 + e]
__global__ void wconv_kernel(const float* __restrict__ w1, const float* __restrict__ w2,
                             const float* __restrict__ wf, const float* __restrict__ w3,
                             u32x4* __restrict__ out) {
    int T = blockIdx.x * 256 + threadIdx.x;   // 16384 threads
    int F = T >> 6, l = T & 63;
    int s = F >> 4, tau = (F >> 3) & 1, ks = F & 7;
    int n16 = l & 15;
    int g = n16 & 3, hl = n16 >> 2;
    const float* W = (g == 0) ? w1 : (g == 1) ? w2 : (g == 2) ? wf : w3;
    const float* src = W + (s * 8 + tau * 4 + hl) * 256 + ks * 32 + (l >> 4) * 8;
    f32x4 lo = *(const f32x4*)src;
    f32x4 hi = *(const f32x4*)(src + 4);
    u32x4 r;
    r[0] = rne1(lo[0]) | (rne1(lo[1]) << 16);
    r[1] = rne1(lo[2]) | (rne1(lo[3]) << 16);
    r[2] = rne1(hi[0]) | (rne1(hi[1]) << 16);
    r[3] = rne1(hi[2]) | (rne1(hi[3]) << 16);
    out[T] = r;
}

// Block: 8 waves (512 thr) = 64 output cols (half row, cg = bid&1).
// Wave w: 8 hcols (s = cg*8+w) x ALL 4 gates via 2 composite n-tiles;
// resident weights = 64 regs -> ~116 unified -> 4 waves/SIMD.
// 128 rows as 8 tiles of 16; A fp32 dbuf in LDS via global_load_lds
// (source-side XOR swizzle). One barrier per tile. Bias folded into acc init.
__global__ __launch_bounds__(512, 4) void lstm_kernel(
    const float* __restrict__ x, const float* __restrict__ h, const float* __restrict__ c,
    const bf16x8* __restrict__ wfrag,
    const float* __restrict__ b1, const float* __restrict__ b2,
    const float* __restrict__ bfv, const float* __restrict__ b3,
    float* __restrict__ out)
{
    __shared__ __align__(16) char smem[2][TILE * 1024];   // 32 KB

    const int tid  = threadIdx.x;
    const int wave = tid >> 6;                // 0..7
    const int lane = tid & 63;
    const int rb   = lane & 15;               // batch row within tile
    const int c4   = lane >> 4;               // 0..3
    const int cg   = blockIdx.x & 1;
    const long row0 = (long)(blockIdx.x >> 1) * NROWB;
    const int s    = cg * 8 + wave;           // 8-hcol slice
    const int col0 = s * 8 + c4;              // tau=0 output col
    const int col1 = col0 + 4;                // tau=1 output col

    // ---- stage tile t (16 rows x 256 fp32) async; source-side XOR swizzle ----
    auto STAGE = [&](int t) {
        char* buf = smem[t & 1];
        const long gr0 = row0 + (long)t * TILE;
#pragma unroll
        for (int i = 0; i < 2; ++i) {
            const int r = wave * 2 + i;
            const unsigned kb = ((unsigned)lane * 16u) ^ (((unsigned)r & 7u) << 4);
            const float* src = (kb < 512u)
                ? (x + (gr0 + r) * 128 + (kb >> 2))
                : (h + (gr0 + r) * 128 + ((kb - 512u) >> 2));
            __builtin_amdgcn_global_load_lds(
                (const __attribute__((address_space(1))) unsigned*)src,
                (__attribute__((address_space(3))) unsigned*)(buf + r * 1024),
                16, 0, 0);
        }
    };

    STAGE(0);

    // ---- resident composite weights: 2 n-tiles x 8 ks -> 64 regs ----
    bf16x8 wfr[2][8];
#pragma unroll
    for (int tau = 0; tau < 2; ++tau)
#pragma unroll
        for (int ks = 0; ks < 8; ++ks)
            wfr[tau][ks] = wfrag[(size_t)((s * 2 + tau) * 8 + ks) * 64 + lane];

    // bias vectors: acc[tau][j] covers (gate j, col tau) -> init value
    f32x4 bias[2];
    bias[0] = (f32x4){ b1[col0], b2[col0], bfv[col0], b3[col0] };
    bias[1] = (f32x4){ b1[col1], b2[col1], bfv[col1], b3[col1] };

    float* out_h = out;
    float* out_c = out + (size_t)B_TOTAL * 128;

#pragma unroll 1
    for (int t = 0; t < NT; ++t) {
        __syncthreads();                  // stage(t) visible; buf(t+1) free

        const long gr0 = row0 + (long)t * TILE;
        const float* crow = c + (gr0 + rb) * 128;
        const float cv0 = crow[col0];
        const float cv1 = crow[col1];

        if (t + 1 < NT) STAGE(t + 1);

        const char* buf = smem[t & 1];

        f32x4 acc[2] = { bias[0], bias[1] };  // bias pre-loaded into acc

#pragma unroll
        for (int ks = 0; ks < 8; ++ks) {
            const unsigned swz = ((unsigned)rb & 7u) << 4;
            const unsigned kb  = (unsigned)(ks * 128 + c4 * 32);
            const char* p = buf + rb * 1024;
            f32x4 a0 = *(const f32x4*)(p + (kb ^ swz));
            f32x4 a1 = *(const f32x4*)(p + ((kb + 16u) ^ swz));
            union { unsigned u[4]; bf16x8 v; } pk;
            pk.u[0] = cvtpk(a0[0], a0[1]);
            pk.u[1] = cvtpk(a0[2], a0[3]);
            pk.u[2] = cvtpk(a1[0], a1[1]);
            pk.u[3] = cvtpk(a1[2], a1[3]);
            acc[0] = __builtin_amdgcn_mfma_f32_16x16x32_bf16(wfr[0][ks], pk.v, acc[0], 0, 0, 0);
            acc[1] = __builtin_amdgcn_mfma_f32_16x16x32_bf16(wfr[1][ks], pk.v, acc[1], 0, 0, 0);
        }

        // epilogue: lane holds all 4 gates of (row rb, col0) and (row rb, col1)
        const long orow = (gr0 + rb) * 128;
#pragma unroll
        for (int tau = 0; tau < 2; ++tau) {
            const float G1 = fsig(acc[tau][0]);
            const float G2 = fsig(acc[tau][1]);
            const float GF = ftanh(acc[tau][2]);
            const float G3 = fsig(acc[tau][3]);
            const float cv = tau ? cv1 : cv0;
            const float nc = cv * G1 + G2 * GF;
            const float nh = ftanh(nc) * G3;
            const int colt = tau ? col1 : col0;
            out_h[orow + colt] = nh;
            out_c[orow + colt] = nc;
        }
    }
}

extern "C" void kernel_launch(void* const* d_in, const int* in_sizes, int n_in,
                              void* d_out, int out_size, void* d_ws, size_t ws_size,
                              hipStream_t stream) {
    (void)in_sizes; (void)n_in; (void)out_size; (void)ws_size;
    const float* x  = (const float*)d_in[0];
    const float* h  = (const float*)d_in[1];
    const float* c  = (const float*)d_in[2];
    const float* W1 = (const float*)d_in[3];
    const float* b1 = (const float*)d_in[4];
    const float* W2 = (const float*)d_in[5];
    const float* b2 = (const float*)d_in[6];
    const float* Wf = (const float*)d_in[7];
    const float* bf = (const float*)d_in[8];
    const float* W3 = (const float*)d_in[9];
    const float* b3 = (const float*)d_in[10];

    wconv_kernel<<<64, 256, 0, stream>>>(W1, W2, Wf, W3, (u32x4*)d_ws);
    lstm_kernel<<<B_TOTAL / NROWB * 2, 512, 0, stream>>>(
        x, h, c, (const bf16x8*)d_ws, b1, b2, bf, b3, (float*)d_out);
}